// Round 2
// baseline (374.703 us; speedup 1.0000x reference)
//
#include <hip/hip_runtime.h>
#include <math.h>

#define U_ 256
#define D_ 5120
#define N_ 16
#define R_ 160

__device__ __forceinline__ float softplus_f(float v) {
    return v > 20.f ? v : log1pf(__expf(v));
}

// ============ K1: tmp[256,160] = x@W1 ; Bm[256,16] = x@BW (split-K, atomic) ===========
#define KB 16
#define NKS 40
#define KSLAB (D_ / NKS)   // 128
#define STG (KSLAB / KB)   // 8

__global__ __launch_bounds__(256) void proj_gemm(
    const float* __restrict__ x, const float* __restrict__ w1,
    const float* __restrict__ bw, float* __restrict__ tmp,
    float* __restrict__ Bm)
{
    const int jt = blockIdx.x;   // 0..10 (10 == B-proj tile)
    const int ks = blockIdx.y;   // 0..NKS-1
    const int t  = threadIdx.x;
    const int uq = t & 63;       // users uq, uq+64, uq+128, uq+192 (strided)
    const int jq = t >> 6;       // wave id; j cols jq*4..+3 (wv broadcast per wave)

    __shared__ float xs[KB][258];   // [k][u], pad 258 -> 2-way (free)
    __shared__ float wsh[KB][16];

    const float* wptr; int ldw, jbase;
    if (jt < 10) { wptr = w1; ldw = R_; jbase = jt * 16; }
    else         { wptr = bw; ldw = N_; jbase = 0; }

    const int k0base = ks * KSLAB;
    const int ux = t >> 2;   // x-load row group
    const int cx = t & 3;

    float acc[4][4];
#pragma unroll
    for (int i = 0; i < 4; ++i)
#pragma unroll
        for (int j = 0; j < 4; ++j) acc[i][j] = 0.f;

    float4 xr[4]; float4 wr = make_float4(0.f, 0.f, 0.f, 0.f);

    auto ld = [&](int s, float4 (&xr_)[4], float4& wr_) {
        const int k0 = k0base + s * KB;
#pragma unroll
        for (int i = 0; i < 4; ++i) {
            const int u = ux + i * 64;
            xr_[i] = *(const float4*)&x[u * D_ + k0 + cx * 4];
        }
        if (t < 64) {
            const int k = t >> 2, c = t & 3;
            wr_ = *(const float4*)&wptr[(k0 + k) * ldw + jbase + c * 4];
        }
    };

    ld(0, xr, wr);

    for (int s = 0; s < STG; ++s) {
#pragma unroll
        for (int i = 0; i < 4; ++i) {
            const int u = ux + i * 64;
            xs[cx * 4 + 0][u] = xr[i].x;
            xs[cx * 4 + 1][u] = xr[i].y;
            xs[cx * 4 + 2][u] = xr[i].z;
            xs[cx * 4 + 3][u] = xr[i].w;
        }
        if (t < 64) {
            const int k = t >> 2, c = t & 3;
            *(float4*)&wsh[k][c * 4] = wr;
        }
        __syncthreads();

        float4 xr2[4]; float4 wr2 = make_float4(0.f, 0.f, 0.f, 0.f);
        if (s + 1 < STG) ld(s + 1, xr2, wr2);

#pragma unroll
        for (int kk = 0; kk < KB; ++kk) {
            const float4 wv = *(const float4*)&wsh[kk][jq * 4];  // wave-broadcast
            float xv[4];
#pragma unroll
            for (int i = 0; i < 4; ++i) xv[i] = xs[kk][uq + i * 64]; // 2-way b32, free
#pragma unroll
            for (int i = 0; i < 4; ++i) {
                acc[i][0] = fmaf(xv[i], wv.x, acc[i][0]);
                acc[i][1] = fmaf(xv[i], wv.y, acc[i][1]);
                acc[i][2] = fmaf(xv[i], wv.z, acc[i][2]);
                acc[i][3] = fmaf(xv[i], wv.w, acc[i][3]);
            }
        }
        __syncthreads();
        if (s + 1 < STG) {
#pragma unroll
            for (int i = 0; i < 4; ++i) xr[i] = xr2[i];
            wr = wr2;
        }
    }

#pragma unroll
    for (int i = 0; i < 4; ++i) {
        const int u = uq + i * 64;
#pragma unroll
        for (int j = 0; j < 4; ++j) {
            const int jc = jq * 4 + j;
            if (jt < 10) atomicAdd(&tmp[u * R_ + jt * 16 + jc], acc[i][j]);
            else         atomicAdd(&Bm[u * N_ + jc], acc[i][j]);
        }
    }
}

// ====== K2: s[u,d] = softplus(tmp@W2 + bias) * x  — 64x64 tile GEMM, K=160 ======
__global__ __launch_bounds__(256) void dt_kernel(
    const float* __restrict__ tmp, const float* __restrict__ w2,
    const float* __restrict__ bias, const float* __restrict__ x,
    float* __restrict__ s)
{
    const int d0 = blockIdx.x * 64;   // 80 tiles
    const int u0 = blockIdx.y * 64;   // 4 tiles
    const int t  = threadIdx.x;
    const int uq = t & 15;            // users u0+uq+16i
    const int dq = t >> 4;            // d cols d0+dq*4..+3

    __shared__ float ts[16][65];      // tmp transposed [r][u]
    __shared__ float wls[16][68];     // w2 [r][d], pad 68 (16B-aligned rows)

    float acc[4][4];
#pragma unroll
    for (int i = 0; i < 4; ++i)
#pragma unroll
        for (int j = 0; j < 4; ++j) acc[i][j] = 0.f;

    for (int r0 = 0; r0 < R_; r0 += 16) {
        {   // stage tmp chunk (transposed)
            const int u = t >> 2, c = t & 3;
            const float4 tv = *(const float4*)&tmp[(u0 + u) * R_ + r0 + c * 4];
            ts[c * 4 + 0][u] = tv.x;
            ts[c * 4 + 1][u] = tv.y;
            ts[c * 4 + 2][u] = tv.z;
            ts[c * 4 + 3][u] = tv.w;
        }
        {   // stage w2 chunk
            const int r = t >> 4, c = t & 15;
            const float4 wv = *(const float4*)&w2[(r0 + r) * D_ + d0 + c * 4];
            *(float4*)&wls[r][c * 4] = wv;
        }
        __syncthreads();
#pragma unroll
        for (int kk = 0; kk < 16; ++kk) {
            const float4 wv = *(const float4*)&wls[kk][dq * 4];
            float av[4];
#pragma unroll
            for (int i = 0; i < 4; ++i) av[i] = ts[kk][uq + i * 16];
#pragma unroll
            for (int i = 0; i < 4; ++i) {
                acc[i][0] = fmaf(av[i], wv.x, acc[i][0]);
                acc[i][1] = fmaf(av[i], wv.y, acc[i][1]);
                acc[i][2] = fmaf(av[i], wv.z, acc[i][2]);
                acc[i][3] = fmaf(av[i], wv.w, acc[i][3]);
            }
        }
        __syncthreads();
    }

    const int d = d0 + dq * 4;
    const float4 bv = *(const float4*)&bias[d];
#pragma unroll
    for (int i = 0; i < 4; ++i) {
        const int u = u0 + uq + 16 * i;
        const float4 xv = *(const float4*)&x[u * D_ + d];
        float4 sv;
        sv.x = softplus_f(acc[i][0] + bv.x) * xv.x;
        sv.y = softplus_f(acc[i][1] + bv.y) * xv.y;
        sv.z = softplus_f(acc[i][2] + bv.z) * xv.z;
        sv.w = softplus_f(acc[i][3] + bv.w) * xv.w;
        *(float4*)&s[u * D_ + d] = sv;
    }
}

// ====== K3: pure stream — out = abar*h + s[u,d]*B[u,n] (float4 over n) ======
__global__ __launch_bounds__(256) void stream_kernel(
    const float* __restrict__ abar, const float* __restrict__ hs,
    const float* __restrict__ s, const float* __restrict__ Bm,
    float* __restrict__ out)
{
    const int u  = blockIdx.y;                 // 0..255
    const int bx = blockIdx.x;                 // 0..19
    const int t  = threadIdx.x;
    const float4* ab4 = (const float4*)abar;
    const float4* h4  = (const float4*)hs;
    const float4* B4  = (const float4*)Bm;
    float4* o4 = (float4*)out;

    const int ubase = u * (D_ * 4);            // f4 units per user = 5120*4
    const float* srow = s + u * D_;

#pragma unroll
    for (int k = 0; k < 4; ++k) {
        const int off = bx * 1024 + k * 256 + t;   // f4 index within user
        const int d   = off >> 2;
        const int n4  = off & 3;
        const int idx = ubase + off;
        const float4 av = ab4[idx];
        const float4 hv = h4[idx];
        const float4 Bv = B4[u * 4 + n4];
        const float  sv = srow[d];
        float4 o;
        o.x = fmaf(av.x, hv.x, sv * Bv.x);
        o.y = fmaf(av.y, hv.y, sv * Bv.y);
        o.z = fmaf(av.z, hv.z, sv * Bv.z);
        o.w = fmaf(av.w, hv.w, sv * Bv.w);
        o4[idx] = o;
    }
}

extern "C" void kernel_launch(void* const* d_in, const int* in_sizes, int n_in,
                              void* d_out, int out_size, void* d_ws, size_t ws_size,
                              hipStream_t stream) {
    const float* x    = (const float*)d_in[0];
    const float* w1   = (const float*)d_in[1];  // [5120,160]
    const float* w2   = (const float*)d_in[2];  // [160,5120]
    const float* bias = (const float*)d_in[3];  // [5120]
    const float* bw   = (const float*)d_in[4];  // [5120,16]
    const float* abar = (const float*)d_in[5];  // [256,5120,16]
    const float* hs   = (const float*)d_in[6];  // [256,5120,16]
    float* out = (float*)d_out;

    float* tmp = (float*)d_ws;                    // [256,160]
    float* Bm  = tmp + U_ * R_;                   // [256,16]
    float* s   = Bm + U_ * N_;                    // [256,5120]

    hipMemsetAsync(d_ws, 0, (size_t)(U_ * R_ + U_ * N_) * sizeof(float), stream);
    proj_gemm<<<dim3(11, NKS), 256, 0, stream>>>(x, w1, bw, tmp, Bm);
    dt_kernel<<<dim3(80, 4), 256, 0, stream>>>(tmp, w2, bias, x, s);
    stream_kernel<<<dim3(20, 256), 256, 0, stream>>>(abar, hs, s, Bm, out);
}

// Round 3
// 264.426 us; speedup vs baseline: 1.4170x; 1.4170x over previous
//
#include <hip/hip_runtime.h>
#include <math.h>

#define U_ 256
#define D_ 5120
#define N_ 16
#define R_ 160
#define J_ 176          // 160 tmp cols + 16 B cols

#define KB 16
#define NKS 20
#define KSLAB (D_ / NKS)   // 256
#define STG (KSLAB / KB)   // 16

__device__ __forceinline__ float softplus_f(float v) {
    return v > 20.f ? v : log1pf(__expf(v));
}

// ===== K1: partial GEMM — P[ks][j][u] += x[u, kslab] @ [W1|BW][kslab, j] =====
// grid (11 j-tiles, NKS k-slabs), block 256. NO atomics: each block owns its
// P[ks][jt*16..+15][0..255] slice and writes it coalesced.
__global__ __launch_bounds__(256) void proj_partial(
    const float* __restrict__ x, const float* __restrict__ w1,
    const float* __restrict__ bw, float* __restrict__ P)
{
    const int jt = blockIdx.x;   // 0..10 (10 == B-proj tile)
    const int ks = blockIdx.y;   // 0..NKS-1
    const int t  = threadIdx.x;
    const int uq = t & 63;       // users uq + 64i
    const int jq = t >> 6;       // wave id; j cols jq*4..+3

    __shared__ float xs[KB][258];   // [k][u], pad -> 2-way (free)
    __shared__ float wsh[KB][16];

    const float* wptr; int ldw, jbase;
    if (jt < 10) { wptr = w1; ldw = R_; jbase = jt * 16; }
    else         { wptr = bw; ldw = N_; jbase = 0; }

    const int k0base = ks * KSLAB;
    const int ux = t >> 2;
    const int cx = t & 3;

    float acc[4][4];
#pragma unroll
    for (int i = 0; i < 4; ++i)
#pragma unroll
        for (int j = 0; j < 4; ++j) acc[i][j] = 0.f;

    float4 xr[4]; float4 wr = make_float4(0.f, 0.f, 0.f, 0.f);

    auto ld = [&](int s, float4 (&xr_)[4], float4& wr_) {
        const int k0 = k0base + s * KB;
#pragma unroll
        for (int i = 0; i < 4; ++i) {
            const int u = ux + i * 64;
            xr_[i] = *(const float4*)&x[u * D_ + k0 + cx * 4];
        }
        if (t < 64) {
            const int k = t >> 2, c = t & 3;
            wr_ = *(const float4*)&wptr[(k0 + k) * ldw + jbase + c * 4];
        }
    };

    ld(0, xr, wr);

    for (int s = 0; s < STG; ++s) {
#pragma unroll
        for (int i = 0; i < 4; ++i) {
            const int u = ux + i * 64;
            xs[cx * 4 + 0][u] = xr[i].x;
            xs[cx * 4 + 1][u] = xr[i].y;
            xs[cx * 4 + 2][u] = xr[i].z;
            xs[cx * 4 + 3][u] = xr[i].w;
        }
        if (t < 64) {
            const int k = t >> 2, c = t & 3;
            *(float4*)&wsh[k][c * 4] = wr;
        }
        __syncthreads();

        float4 xr2[4]; float4 wr2 = make_float4(0.f, 0.f, 0.f, 0.f);
        if (s + 1 < STG) ld(s + 1, xr2, wr2);

#pragma unroll
        for (int kk = 0; kk < KB; ++kk) {
            const float4 wv = *(const float4*)&wsh[kk][jq * 4];  // wave-broadcast
            float xv[4];
#pragma unroll
            for (int i = 0; i < 4; ++i) xv[i] = xs[kk][uq + i * 64]; // 2-way, free
#pragma unroll
            for (int i = 0; i < 4; ++i) {
                acc[i][0] = fmaf(xv[i], wv.x, acc[i][0]);
                acc[i][1] = fmaf(xv[i], wv.y, acc[i][1]);
                acc[i][2] = fmaf(xv[i], wv.z, acc[i][2]);
                acc[i][3] = fmaf(xv[i], wv.w, acc[i][3]);
            }
        }
        __syncthreads();
        if (s + 1 < STG) {
#pragma unroll
            for (int i = 0; i < 4; ++i) xr[i] = xr2[i];
            wr = wr2;
        }
    }

    // coalesced partial write: P[(ks*J_ + jglob)*256 + u]
#pragma unroll
    for (int j = 0; j < 4; ++j) {
        const int jglob = jt * 16 + jq * 4 + j;
        float* row = P + ((size_t)ks * J_ + jglob) * 256;
#pragma unroll
        for (int i = 0; i < 4; ++i) row[uq + i * 64] = acc[i][j];
    }
}

// ===== K2: reduce over NKS slabs -> tmpT[r][u] (transposed) and Bm[u][n] =====
__global__ __launch_bounds__(256) void reduce_kernel(
    const float* __restrict__ P, float* __restrict__ tmpT,
    float* __restrict__ Bm)
{
    const int j = blockIdx.x;    // 0..175
    const int u = threadIdx.x;   // 0..255
    float sum = 0.f;
#pragma unroll
    for (int ks = 0; ks < NKS; ++ks)
        sum += P[((size_t)ks * J_ + j) * 256 + u];
    if (j < R_) tmpT[j * 256 + u] = sum;        // coalesced
    else        Bm[u * N_ + (j - R_)] = sum;    // scattered, 16 KB total
}

// ===== K3: s[u,d] = softplus(tmpT^T @ W2 + bias) * x — 64x64 tiles, K=160 =====
__global__ __launch_bounds__(256) void dt_kernel(
    const float* __restrict__ tmpT, const float* __restrict__ w2,
    const float* __restrict__ bias, const float* __restrict__ x,
    float* __restrict__ s)
{
    const int d0 = blockIdx.x * 64;   // 80 tiles
    const int u0 = blockIdx.y * 64;   // 4 tiles
    const int t  = threadIdx.x;
    const int uq = t & 15;            // users u0+uq+16i
    const int dq = t >> 4;            // d cols d0+dq*4..+3

    __shared__ float ts[16][68];      // tmpT chunk [r][u-in-tile]
    __shared__ float wls[16][68];     // w2 chunk [r][d-in-tile]

    float acc[4][4];
#pragma unroll
    for (int i = 0; i < 4; ++i)
#pragma unroll
        for (int j = 0; j < 4; ++j) acc[i][j] = 0.f;

    const int rr = t >> 4, cc = t & 15;   // staging coords (16 rows x 16 f4-cols)

    for (int r0 = 0; r0 < R_; r0 += 16) {
        // tmpT is already [r][u]: direct coalesced copy
        *(float4*)&ts[rr][cc * 4]  = *(const float4*)&tmpT[(r0 + rr) * 256 + u0 + cc * 4];
        *(float4*)&wls[rr][cc * 4] = *(const float4*)&w2[(r0 + rr) * D_ + d0 + cc * 4];
        __syncthreads();
#pragma unroll
        for (int kk = 0; kk < 16; ++kk) {
            const float4 wv = *(const float4*)&wls[kk][dq * 4];
            float av[4];
#pragma unroll
            for (int i = 0; i < 4; ++i) av[i] = ts[kk][uq + i * 16];
#pragma unroll
            for (int i = 0; i < 4; ++i) {
                acc[i][0] = fmaf(av[i], wv.x, acc[i][0]);
                acc[i][1] = fmaf(av[i], wv.y, acc[i][1]);
                acc[i][2] = fmaf(av[i], wv.z, acc[i][2]);
                acc[i][3] = fmaf(av[i], wv.w, acc[i][3]);
            }
        }
        __syncthreads();
    }

    const int d = d0 + dq * 4;
    const float4 bv = *(const float4*)&bias[d];
#pragma unroll
    for (int i = 0; i < 4; ++i) {
        const int u = u0 + uq + 16 * i;
        const float4 xv = *(const float4*)&x[u * D_ + d];
        float4 sv;
        sv.x = softplus_f(acc[i][0] + bv.x) * xv.x;
        sv.y = softplus_f(acc[i][1] + bv.y) * xv.y;
        sv.z = softplus_f(acc[i][2] + bv.z) * xv.z;
        sv.w = softplus_f(acc[i][3] + bv.w) * xv.w;
        *(float4*)&s[u * D_ + d] = sv;
    }
}

// ===== K4: pure stream — out = abar*h + s[u,d]*B[u,n] (float4 over n) =====
__global__ __launch_bounds__(256) void stream_kernel(
    const float* __restrict__ abar, const float* __restrict__ hs,
    const float* __restrict__ s, const float* __restrict__ Bm,
    float* __restrict__ out)
{
    const int u  = blockIdx.y;                 // 0..255
    const int bx = blockIdx.x;                 // 0..19
    const int t  = threadIdx.x;
    const float4* ab4 = (const float4*)abar;
    const float4* h4  = (const float4*)hs;
    const float4* B4  = (const float4*)Bm;
    float4* o4 = (float4*)out;

    const int ubase = u * (D_ * 4);            // f4 units per user
    const float* srow = s + u * D_;

#pragma unroll
    for (int k = 0; k < 4; ++k) {
        const int off = bx * 1024 + k * 256 + t;
        const int d   = off >> 2;
        const int n4  = off & 3;
        const int idx = ubase + off;
        const float4 av = ab4[idx];
        const float4 hv = h4[idx];
        const float4 Bv = B4[u * 4 + n4];
        const float  sv = srow[d];
        float4 o;
        o.x = fmaf(av.x, hv.x, sv * Bv.x);
        o.y = fmaf(av.y, hv.y, sv * Bv.y);
        o.z = fmaf(av.z, hv.z, sv * Bv.z);
        o.w = fmaf(av.w, hv.w, sv * Bv.w);
        o4[idx] = o;
    }
}

extern "C" void kernel_launch(void* const* d_in, const int* in_sizes, int n_in,
                              void* d_out, int out_size, void* d_ws, size_t ws_size,
                              hipStream_t stream) {
    const float* x    = (const float*)d_in[0];
    const float* w1   = (const float*)d_in[1];  // [5120,160]
    const float* w2   = (const float*)d_in[2];  // [160,5120]
    const float* bias = (const float*)d_in[3];  // [5120]
    const float* bw   = (const float*)d_in[4];  // [5120,16]
    const float* abar = (const float*)d_in[5];  // [256,5120,16]
    const float* hs   = (const float*)d_in[6];  // [256,5120,16]
    float* out = (float*)d_out;

    float* P    = (float*)d_ws;                 // [NKS,176,256]  3.6 MB
    float* tmpT = P + (size_t)NKS * J_ * 256;   // [160,256]
    float* Bm   = tmpT + R_ * 256;              // [256,16]
    float* s    = Bm + U_ * N_;                 // [256,5120]

    proj_partial<<<dim3(11, NKS), 256, 0, stream>>>(x, w1, bw, P);
    reduce_kernel<<<dim3(J_), 256, 0, stream>>>(P, tmpT, Bm);
    dt_kernel<<<dim3(80, 4), 256, 0, stream>>>(tmpT, w2, bias, x, s);
    stream_kernel<<<dim3(20, 256), 256, 0, stream>>>(abar, hs, s, Bm, out);
}